// Round 16
// baseline (349.101 us; speedup 1.0000x reference)
//
#include <hip/hip_runtime.h>
#include <hip/hip_bf16.h>
#include <stdint.h>

// GraphConv x2 — round 16: r15 base (349us best) + fill ∥ gemm1 retry with
// ZERO-LDS gemm path (r13's failure was LDS-starved fill occupancy):
//   - weights pre-packed k-major P[k4][d][4] in spare blocks of hist launch
//   - x rows via wave-uniform scalar loads; weights via coalesced dwordx4 (L1)
//   - no __shared__ in the fused kernel -> fill keeps 32 waves/CU
//   Pipeline: hist+pack -> scan1-3 -> [fill ∥ gemm1] -> gather1_fused -> gather2
// N=100000, E=1600000, D=64

#define D 64
#define SCAN_CHUNK 1024

typedef unsigned int   u32;
typedef unsigned short u16;

__device__ __forceinline__ float bf2f(u16 v) {
    return __uint_as_float(((u32)v) << 16);
}
__device__ __forceinline__ u16 f2bf(float f) {
    u32 u = __float_as_uint(f);
    u32 r = (u + 0x7fffu + ((u >> 16) & 1u)) >> 16;   // round-to-nearest-even
    return (u16)r;
}

// ---------------- hist + weight-pack (pack rides in spare blocks) ----------------
// pack: P[m][o] with o = k4*256 + d*4 + kk  <-  W_m[d*64 + k4*4 + kk]
__global__ __launch_bounds__(256) void hist_pack_kernel(
    const int* __restrict__ ei, int* __restrict__ deg, int E_,
    const float* __restrict__ Wrel1, const float* __restrict__ Wroot1,
    float* __restrict__ packed, int eBlocks)
{
    int b = blockIdx.x;
    if (b >= eBlocks) {
        int t = (b - eBlocks) * 256 + threadIdx.x;   // 0..8191
        if (t >= 2 * D * D) return;
        int m   = t >> 12;                            // 0: Wrel1, 1: Wroot1
        int o   = t & 4095;
        int k4  = o >> 8;
        int d   = (o >> 2) & 63;
        int kk  = o & 3;
        const float* W = m ? Wroot1 : Wrel1;
        packed[(size_t)m * D * D + o] = W[d * 64 + k4 * 4 + kk];
        return;
    }
    int e = b * 256 + threadIdx.x;
    if (e >= E_) return;
    atomicAdd(&deg[ei[E_ + e]], 1);
}

// ---------------- scans (r15 verbatim, proven) ----------------
__global__ __launch_bounds__(256) void scan1_kernel(
    const int* __restrict__ deg, int* __restrict__ loc, int* __restrict__ partial, int n)
{
    __shared__ int wsum[4];
    int t = threadIdx.x;
    int base = blockIdx.x * SCAN_CHUNK + t * 4;
    int v0 = (base + 0 < n) ? deg[base + 0] : 0;
    int v1 = (base + 1 < n) ? deg[base + 1] : 0;
    int v2 = (base + 2 < n) ? deg[base + 2] : 0;
    int v3 = (base + 3 < n) ? deg[base + 3] : 0;
    int s = v0 + v1 + v2 + v3;
    int lane = t & 63, wave = t >> 6;
    int inc = s;
    for (int off = 1; off < 64; off <<= 1) {
        int u = __shfl_up(inc, off);
        if (lane >= off) inc += u;
    }
    if (lane == 63) wsum[wave] = inc;
    __syncthreads();
    int woff = 0;
    for (int w = 0; w < wave; ++w) woff += wsum[w];
    int ex = woff + inc - s;
    if (base + 0 < n) loc[base + 0] = ex;
    if (base + 1 < n) loc[base + 1] = ex + v0;
    if (base + 2 < n) loc[base + 2] = ex + v0 + v1;
    if (base + 3 < n) loc[base + 3] = ex + v0 + v1 + v2;
    if (t == 255) partial[blockIdx.x] = woff + inc;
}

__global__ __launch_bounds__(1024) void scan2_kernel(int* __restrict__ partial, int nchunk)
{
    __shared__ int sd[1024];
    int t = threadIdx.x;
    if (t < nchunk) sd[t] = partial[t];
    __syncthreads();
    if (t == 0) {
        int run = 0;
        for (int i = 0; i < nchunk; ++i) { int v = sd[i]; sd[i] = run; run += v; }
    }
    __syncthreads();
    if (t < nchunk) partial[t] = sd[t];
}

__global__ __launch_bounds__(256) void scan3_kernel(
    int* __restrict__ rowptr, const int* __restrict__ partial,
    int* __restrict__ cursor, int n, int Etot)
{
    int i = blockIdx.x * 256 + threadIdx.x;
    if (i == 0) rowptr[n] = Etot;
    if (i >= n) return;
    int v = rowptr[i] + partial[i >> 10];
    rowptr[i] = v;
    cursor[i] = v;
}

// ---------------- heterogeneous: fill (blocks < nFill) ∥ gemm1 (rest), ZERO LDS ----------------
// fill:  pairs[cursor[dst]++] = (src,w)            [r10-fastest store variant]
// gemm1: xr1[i] = x[i]@Wrel1^T (bf16); io[i] = x[i]@Wroot1^T + b1 (f32)
//        weights from packed P (coalesced dwordx4, L1); x via uniform s_load.
#define GW 8   // waves/block (512 threads)
#define GR 4   // rows/wave
__global__ __launch_bounds__(512) void fill_gemm1_kernel(
    const int* __restrict__ ei, const float* __restrict__ ew,
    int* __restrict__ cursor, uint64_t* __restrict__ pairs, int E_,
    const float* __restrict__ x, const float* __restrict__ packed,
    const float* __restrict__ brel,
    u16* __restrict__ xr, float* __restrict__ io, int Nn, int nFill)
{
    int tid = threadIdx.x;

    if ((int)blockIdx.x < nFill) {
        // ---- fill path: no LDS, low VGPR, full occupancy ----
        int e = (int)blockIdx.x * 512 + tid;
        if (e >= E_) return;
        int src = ei[e];
        int dst = ei[E_ + e];
        int p = atomicAdd(&cursor[dst], 1);
        uint64_t packed64 = (uint64_t)(u32)src | ((uint64_t)__float_as_uint(ew[e]) << 32);
        __hip_atomic_store(&pairs[p], packed64, __ATOMIC_RELAXED, __HIP_MEMORY_SCOPE_SYSTEM);
        return;
    }

    // ---- gemm1 path: zero LDS ----
    int wave = tid >> 6, lane = tid & 63;
    int base = (((int)blockIdx.x - nFill) * GW + wave) * GR;
    if (base >= Nn) return;
    base = __builtin_amdgcn_readfirstlane(base);
    int nr = min(GR, Nn - base);

    const float4* WrelP  = (const float4*)packed;             // [16][64] float4
    const float4* WrootP = (const float4*)(packed + D * D);   // [16][64] float4
    float blane = brel[lane];

    float aR[GR] = {0.f, 0.f, 0.f, 0.f};
    float aC[GR] = {0.f, 0.f, 0.f, 0.f};
#pragma unroll
    for (int k4 = 0; k4 < 16; ++k4) {
        float4 wr = WrelP [k4 * 64 + lane];   // coalesced 1KB, L1-resident
        float4 wc = WrootP[k4 * 64 + lane];
#pragma unroll
        for (int r = 0; r < GR; ++r) {
            int row = (r < nr) ? (base + r) : base;           // clamp, wave-uniform
            const float4 xv = *reinterpret_cast<const float4*>(
                x + (size_t)row * D + k4 * 4);                // uniform -> s_load
            aR[r] = fmaf(xv.x, wr.x, aR[r]); aR[r] = fmaf(xv.y, wr.y, aR[r]);
            aR[r] = fmaf(xv.z, wr.z, aR[r]); aR[r] = fmaf(xv.w, wr.w, aR[r]);
            aC[r] = fmaf(xv.x, wc.x, aC[r]); aC[r] = fmaf(xv.y, wc.y, aC[r]);
            aC[r] = fmaf(xv.z, wc.z, aC[r]); aC[r] = fmaf(xv.w, wc.w, aC[r]);
        }
    }
    for (int r = 0; r < nr; ++r) {
        size_t o = (size_t)(base + r) * D + lane;
        xr[o] = f2bf(aR[r]);
        io[o] = aC[r] + blane;
    }
}

// ---------------- gather1_fused (r15 verbatim, proven) ----------------
__global__ __launch_bounds__(512) void gather1_fused(
    const u16* __restrict__ xr1, const uint64_t* __restrict__ pairs,
    const int* __restrict__ rowptr,
    const float* __restrict__ Wrel, const float* __restrict__ brel,
    const float* __restrict__ Wroot,
    u16* __restrict__ xr2, float* __restrict__ io, int Nn)
{
    __shared__ float WrelT[D][D + 1];
    __shared__ float WrootT[D][D + 1];
    __shared__ float bias[D];
    __shared__ float rowH[GW][D];

    int tid = threadIdx.x;
    for (int i2 = tid; i2 < D * D; i2 += 512) {
        int d = i2 >> 6, k = i2 & 63;
        WrelT [k][d] = Wrel [i2];
        WrootT[k][d] = Wroot[i2];
    }
    if (tid < D) bias[tid] = brel[tid];
    __syncthreads();

    int wave = tid >> 6, lane = tid & 63;
    int i = (int)blockIdx.x * GW + wave;
    if (i >= Nn) return;                       // wave-uniform, after barrier

    int beg = __builtin_amdgcn_readfirstlane(rowptr[i]);
    int end = __builtin_amdgcn_readfirstlane(rowptr[i + 1]);

    float acc = 0.f;
    for (int b = beg; b < end; b += 8) {
#pragma unroll
        for (int jj = 0; jj < 8; ++jj) {
            uint64_t p = pairs[b + jj];        // uniform s_load_dwordx2 (pad past E)
            int   s  = (int)(u32)p;
            float wr = __uint_as_float((u32)(p >> 32));
            bool valid = (b + jj) < end;       // scalar tail select
            s = valid ? s : 0;
            float w = valid ? wr : 0.f;
            float v = bf2f(xr1[(size_t)s * D + lane]);  // SGPR base + lane offset
            acc = fmaf(v, w, acc);
        }
    }

    size_t o = (size_t)i * D + lane;
    float h = fmaxf(acc + io[o], 0.f);         // ReLU

    rowH[wave][lane] = h;
    // same-wave LDS write->read (proven)

    const float4* rH4 = reinterpret_cast<const float4*>(rowH[wave]);
    float aR = 0.f;
    float aC = bias[lane];
#pragma unroll
    for (int k4 = 0; k4 < 16; ++k4) {
        float4 hv = rH4[k4];                   // broadcast b128
        int k = k4 * 4;
        aR = fmaf(hv.x, WrelT [k + 0][lane], aR);
        aR = fmaf(hv.y, WrelT [k + 1][lane], aR);
        aR = fmaf(hv.z, WrelT [k + 2][lane], aR);
        aR = fmaf(hv.w, WrelT [k + 3][lane], aR);
        aC = fmaf(hv.x, WrootT[k + 0][lane], aC);
        aC = fmaf(hv.y, WrootT[k + 1][lane], aC);
        aC = fmaf(hv.z, WrootT[k + 2][lane], aC);
        aC = fmaf(hv.w, WrootT[k + 3][lane], aC);
    }
    xr2[o] = f2bf(aR);
    io[o]  = aC;        // row i fully owned by this wave
}

// ---------------- gather2 (r15 verbatim, proven) ----------------
#define AW 8
__global__ __launch_bounds__(512) void gather2_kernel(
    const u16* __restrict__ xr, const uint64_t* __restrict__ pairs,
    const int* __restrict__ rowptr, float* __restrict__ io, int Nn)
{
    int tid  = threadIdx.x;
    int wave = tid >> 6, lane = tid & 63;
    int i = blockIdx.x * AW + wave;
    if (i >= Nn) return;                       // wave-uniform

    int beg = __builtin_amdgcn_readfirstlane(rowptr[i]);
    int end = __builtin_amdgcn_readfirstlane(rowptr[i + 1]);

    float acc = 0.f;
    for (int b = beg; b < end; b += 8) {
#pragma unroll
        for (int jj = 0; jj < 8; ++jj) {
            uint64_t p = pairs[b + jj];
            int   s  = (int)(u32)p;
            float wr = __uint_as_float((u32)(p >> 32));
            bool valid = (b + jj) < end;
            s = valid ? s : 0;
            float w = valid ? wr : 0.f;
            float v = bf2f(xr[(size_t)s * D + lane]);
            acc = fmaf(v, w, acc);
        }
    }
    size_t o = (size_t)i * D + lane;
    io[o] = acc + io[o];
}

extern "C" void kernel_launch(void* const* d_in, const int* in_sizes, int n_in,
                              void* d_out, int out_size, void* d_ws, size_t ws_size,
                              hipStream_t stream)
{
    const float* x      = (const float*)d_in[0];
    const int*   ei     = (const int*)  d_in[1];
    const float* ew     = (const float*)d_in[2];
    const float* Wrel1  = (const float*)d_in[3];
    const float* brel1  = (const float*)d_in[4];
    const float* Wroot1 = (const float*)d_in[5];
    const float* Wrel2  = (const float*)d_in[6];
    const float* brel2  = (const float*)d_in[7];
    const float* Wroot2 = (const float*)d_in[8];
    float* out = (float*)d_out;

    const int E_ = in_sizes[2];          // 1600000
    const int Nn = in_sizes[0] / D;      // 100000

    // workspace layout — ~39.3 MB (proven fit), + packed weights 32KB
    char* w = (char*)d_ws;
    size_t off = 0;
    u16*  xr1    = (u16*)(w + off); off += (size_t)Nn * D * sizeof(u16);   // 12.8 MB
    u16*  xr2    = (u16*)(w + off); off += (size_t)Nn * D * sizeof(u16);   // 12.8 MB
    int*  rowptr = (int*)(w + off); off += (size_t)(Nn + 1) * sizeof(int);
    int*  cursor = (int*)(w + off); off += (size_t)Nn * sizeof(int);
    int*  partial= (int*)(w + off); off += 1024 * sizeof(int);
    off = (off + 15) & ~(size_t)15;
    float* packed = (float*)(w + off); off += 2 * D * D * sizeof(float);   // 32 KB
    off = (off + 15) & ~(size_t)15;
    uint64_t* pairs = (uint64_t*)(w + off);                                // 12.8 MB + pad

    const int nchunk  = (Nn + SCAN_CHUNK - 1) / SCAN_CHUNK;
    const int eBlocks = (E_ + 255) / 256;
    const int packBlocks = (2 * D * D + 255) / 256;        // 32
    const int nFill   = (E_ + 511) / 512;                  // 3125
    const int nGemm   = (Nn + GW * GR - 1) / (GW * GR);    // 3125
    const int g1Blocks = (Nn + GW - 1) / GW;
    const int g2Blocks = (Nn + AW - 1) / AW;

    // ---- CSR front (+ weight pack riding on hist) ----
    (void)hipMemsetAsync(cursor, 0, (size_t)Nn * sizeof(int), stream);
    hist_pack_kernel<<<eBlocks + packBlocks, 256, 0, stream>>>(
        ei, cursor, E_, Wrel1, Wroot1, packed, eBlocks);
    scan1_kernel<<<nchunk, 256, 0, stream>>>(cursor, rowptr, partial, Nn);
    scan2_kernel<<<1, 1024, 0, stream>>>(partial, nchunk);
    scan3_kernel<<<(Nn + 255) / 256, 256, 0, stream>>>(rowptr, partial, cursor, Nn, E_);

    // ---- fill ∥ gemm1 (heterogeneous, zero LDS) ----
    fill_gemm1_kernel<<<nFill + nGemm, 512, 0, stream>>>(
        ei, ew, cursor, pairs, E_, x, packed, brel1, xr1, out, Nn, nFill);

    // ---- gather1 + relu + layer-2 pre-transform (fused epilogue) ----
    gather1_fused<<<g1Blocks, 512, 0, stream>>>(xr1, pairs, rowptr,
                                                Wrel2, brel2, Wroot2, xr2, out, Nn);
    // ---- gather2 (final) ----
    gather2_kernel<<<g2Blocks, 512, 0, stream>>>(xr2, pairs, rowptr, out, Nn);
}